// Round 6
// baseline (302.267 us; speedup 1.0000x reference)
//
#include <hip/hip_runtime.h>
#include <cstdint>
#include <cstddef>

typedef __bf16 bf16;
typedef __attribute__((ext_vector_type(8))) __bf16 bf16x8;
typedef __attribute__((ext_vector_type(4))) __bf16 bf16x4;
typedef __attribute__((ext_vector_type(4))) float f32x4;
typedef __attribute__((ext_vector_type(4))) short s16x4;

#define S_LEN   2048
#define WIN     512
#define NH_Q    16
#define NH_KV   4
#define HD_     128
#define NTOK    4096   // B * S

#if defined(__has_builtin)
#if __has_builtin(__builtin_amdgcn_mfma_f32_16x16x16bf16_1k)
#define HAVE_MFMA16 1
#endif
#endif
#ifndef HAVE_MFMA16
#define HAVE_MFMA16 0
#endif

// async global->LDS, 16B per lane; LDS dest = wave-uniform base + lane*16
__device__ __forceinline__ void async_copy16(const void* g, void* l) {
  __builtin_amdgcn_global_load_lds(
      (const __attribute__((address_space(1))) void*)g,
      (__attribute__((address_space(3))) void*)l, 16, 0, 0);
}

// ---------------- fp32 -> bf16 convert, all 5 arrays in one launch ----------
__global__ __launch_bounds__(256)
void cvt_all(const float* __restrict__ hs, const float* __restrict__ wq,
             const float* __restrict__ wk, const float* __restrict__ wv,
             const float* __restrict__ wo, bf16* __restrict__ hsb,
             bf16* __restrict__ wqb, bf16* __restrict__ wkb,
             bf16* __restrict__ wvb, bf16* __restrict__ wob) {
  long i = ((long)blockIdx.x * 256 + threadIdx.x) * 4;  // < 18874368
  const float* in;
  bf16* out;
  if (i < 8388608)       { in = hs + i;            out = hsb + i; }
  else if (i < 12582912) { in = wq + (i - 8388608); out = wqb + (i - 8388608); }
  else if (i < 13631488) { in = wk + (i - 12582912); out = wkb + (i - 12582912); }
  else if (i < 14680064) { in = wv + (i - 13631488); out = wvb + (i - 13631488); }
  else                   { in = wo + (i - 14680064); out = wob + (i - 14680064); }
  float4 v = *(const float4*)in;
  bf16x4 t = {(bf16)v.x, (bf16)v.y, (bf16)v.z, (bf16)v.w};
  *(bf16x4*)out = t;
}

// ===== bank-conflict swizzle ================================================
// Tile rows are 32 elems = 16 dwords -> for fixed quad, 16 rows hit only 2
// bank-groups (8-way conflict, 2.94x -- m136). Rotate the four 16B k-groups
// within each row by (row>>1): staging lane l loads global group
// ((l&3)+((l>>3)&3))&3; frag reads fetch position (quad-(row>>1))&3. Rows
// 0..7 then cycle all 4 groups -> exactly 2-way aliasing = free (m136).
// global_load_lds's lane-linear LDS dest is untouched (we permute the SOURCE
// address only); per-row 64B global segments stay fully coalesced.

// ---------------- GEMM: C[M][N] = A[M][K] @ W[N][K]^T -----------------------
// 128x128 tile, BK=32, dbuf, 4 waves 2x2, swizzled LDS (see above).
template <typename OutT>
__global__ __launch_bounds__(256)
void gemm_bt(const bf16* __restrict__ A, const bf16* __restrict__ W,
             OutT* __restrict__ C, int M, int N, int K) {
  __shared__ __align__(16) bf16 As[2][128 * 32];
  __shared__ __align__(16) bf16 Bs[2][128 * 32];
  const int tid  = threadIdx.x;
  const int wave = tid >> 6, lane = tid & 63;
  const int quad = lane >> 4, l16 = lane & 15;
  const int wm = wave >> 1, wn = wave & 1;
  const int m0 = blockIdx.y * 128, n0 = blockIdx.x * 128;
  const int lrow = lane >> 2;                        // row within 16-row chunk
  const int lcol = (((lane & 3) + ((lane >> 3) & 3)) & 3) * 8;  // swizzled src k
  const int gfrag = ((quad - ((l16 >> 1) & 3)) & 3) * 8;        // swizzled read k

  f32x4 acc[4][4];
#pragma unroll
  for (int i = 0; i < 4; ++i)
#pragma unroll
    for (int j = 0; j < 4; ++j) acc[i][j] = (f32x4){0.f, 0.f, 0.f, 0.f};

  auto stage = [&](int buf, int k0) {
#pragma unroll
    for (int it = 0; it < 2; ++it) {
      const int c   = it * 4 + wave;
      const int row = c * 16 + lrow;
      async_copy16(A + (size_t)(m0 + row) * K + k0 + lcol, &As[buf][c * 512]);
      async_copy16(W + (size_t)(n0 + row) * K + k0 + lcol, &Bs[buf][c * 512]);
    }
  };

  stage(0, 0);
  __syncthreads();
  for (int k0 = 0; k0 < K; k0 += 32) {
    const int cur = (k0 >> 5) & 1;
    if (k0 + 32 < K) stage(cur ^ 1, k0 + 32);
    bf16x8 af[4], bfr[4];
#pragma unroll
    for (int mt = 0; mt < 4; ++mt)
      af[mt] = *(const bf16x8*)&As[cur][(wm * 64 + mt * 16 + l16) * 32 + gfrag];
#pragma unroll
    for (int nt = 0; nt < 4; ++nt)
      bfr[nt] = *(const bf16x8*)&Bs[cur][(wn * 64 + nt * 16 + l16) * 32 + gfrag];
#pragma unroll
    for (int mt = 0; mt < 4; ++mt)
#pragma unroll
      for (int nt = 0; nt < 4; ++nt)
        acc[mt][nt] = __builtin_amdgcn_mfma_f32_16x16x32_bf16(
            af[mt], bfr[nt], acc[mt][nt], 0, 0, 0);
    __syncthreads();
  }
#pragma unroll
  for (int mt = 0; mt < 4; ++mt)
#pragma unroll
    for (int nt = 0; nt < 4; ++nt)
#pragma unroll
      for (int r = 0; r < 4; ++r) {
        const int row = m0 + wm * 64 + mt * 16 + quad * 4 + r;
        const int col = n0 + wn * 64 + nt * 16 + l16;
        C[(size_t)row * N + col] = (OutT)acc[mt][nt][r];
      }
}

// ---------------- fused QKV GEMM + RoPE + V-transpose (swizzled) ------------
// grid.x = 24: bx 0..15 -> Q, 16..19 -> K, 20..23 -> V. grid.y = 32.
__global__ __launch_bounds__(256)
void gemm_qkv(const bf16* __restrict__ A, const bf16* __restrict__ Wq,
              const bf16* __restrict__ Wk, const bf16* __restrict__ Wv,
              bf16* __restrict__ Qo, bf16* __restrict__ Ko,
              bf16* __restrict__ Vt) {
  __shared__ __align__(16) bf16 As[2][128 * 32];
  __shared__ __align__(16) bf16 Bs[2][128 * 32];
  const int tid  = threadIdx.x;
  const int wave = tid >> 6, lane = tid & 63;
  const int quad = lane >> 4, l16 = lane & 15;
  const int wm = wave >> 1, wn = wave & 1;
  const int bx = blockIdx.x;
  const int m0 = blockIdx.y * 128;
  const int region = (bx < 16) ? 0 : (bx < 20 ? 1 : 2);
  const bf16* W = (region == 0) ? Wq + (size_t)bx * 128 * 2048
                : (region == 1) ? Wk + (size_t)(bx - 16) * 128 * 2048
                                : Wv + (size_t)(bx - 20) * 128 * 2048;
  const int lrow = lane >> 2;
  const int lcol = (((lane & 3) + ((lane >> 3) & 3)) & 3) * 8;
  const int gfrag = ((quad - ((l16 >> 1) & 3)) & 3) * 8;

  f32x4 acc[4][4];
#pragma unroll
  for (int i = 0; i < 4; ++i)
#pragma unroll
    for (int j = 0; j < 4; ++j) acc[i][j] = (f32x4){0.f, 0.f, 0.f, 0.f};

  auto stage = [&](int buf, int k0) {
#pragma unroll
    for (int it = 0; it < 2; ++it) {
      const int c   = it * 4 + wave;
      const int row = c * 16 + lrow;
      async_copy16(A + (size_t)(m0 + row) * 2048 + k0 + lcol, &As[buf][c * 512]);
      async_copy16(W + (size_t)row * 2048 + k0 + lcol, &Bs[buf][c * 512]);
    }
  };

  stage(0, 0);
  __syncthreads();
  for (int k0 = 0; k0 < 2048; k0 += 32) {
    const int cur = (k0 >> 5) & 1;
    if (k0 + 32 < 2048) stage(cur ^ 1, k0 + 32);
    bf16x8 af[4], bfr[4];
#pragma unroll
    for (int mt = 0; mt < 4; ++mt)
      af[mt] = *(const bf16x8*)&As[cur][(wm * 64 + mt * 16 + l16) * 32 + gfrag];
#pragma unroll
    for (int nt = 0; nt < 4; ++nt)
      bfr[nt] = *(const bf16x8*)&Bs[cur][(wn * 64 + nt * 16 + l16) * 32 + gfrag];
#pragma unroll
    for (int mt = 0; mt < 4; ++mt)
#pragma unroll
      for (int nt = 0; nt < 4; ++nt)
        acc[mt][nt] = __builtin_amdgcn_mfma_f32_16x16x32_bf16(
            af[mt], bfr[nt], acc[mt][nt], 0, 0, 0);
    __syncthreads();
  }

  // fused RoPE (Q and K regions, wn==0 waves only; wave-uniform branch)
  if (region < 2 && wn == 0) {
#pragma unroll
    for (int nt = 0; nt < 2; ++nt) {
      const int d = nt * 16 + l16;  // 0..31
      const float invf = exp2f(-(float)d * 0.41524101186091903f);  // 10000^(-d/32)
#pragma unroll
      for (int mt = 0; mt < 4; ++mt)
#pragma unroll
        for (int r = 0; r < 4; ++r) {
          const int pos = (m0 + wm * 64 + mt * 16 + quad * 4 + r) & (S_LEN - 1);
          float s, c;
          __sincosf((float)pos * invf, &s, &c);
          const float x1 = acc[mt][nt][r], x2 = acc[mt][nt + 2][r];
          acc[mt][nt][r]     = x1 * c - x2 * s;
          acc[mt][nt + 2][r] = x2 * c + x1 * s;
        }
    }
  }

  if (region == 0) {  // Q: [tok][2048]
#pragma unroll
    for (int mt = 0; mt < 4; ++mt)
#pragma unroll
      for (int nt = 0; nt < 4; ++nt)
#pragma unroll
        for (int r = 0; r < 4; ++r) {
          const int row = m0 + wm * 64 + mt * 16 + quad * 4 + r;
          const int col = bx * 128 + wn * 64 + nt * 16 + l16;
          Qo[(size_t)row * 2048 + col] = (bf16)acc[mt][nt][r];
        }
  } else if (region == 1) {  // K: [tok][512]
#pragma unroll
    for (int mt = 0; mt < 4; ++mt)
#pragma unroll
      for (int nt = 0; nt < 4; ++nt)
#pragma unroll
        for (int r = 0; r < 4; ++r) {
          const int row = m0 + wm * 64 + mt * 16 + quad * 4 + r;
          const int col = (bx - 16) * 128 + wn * 64 + nt * 16 + l16;
          Ko[(size_t)row * 512 + col] = (bf16)acc[mt][nt][r];
        }
  } else {  // V: transposed -> vt[(b*4+kv)*128 + d][s]; 4 consecutive s/lane
#pragma unroll
    for (int mt = 0; mt < 4; ++mt) {
      const int row0 = m0 + wm * 64 + mt * 16 + quad * 4;
      const int b = row0 >> 11, s0 = row0 & (S_LEN - 1);
#pragma unroll
      for (int nt = 0; nt < 4; ++nt) {
        const int colv = (bx - 20) * 128 + wn * 64 + nt * 16 + l16;  // 0..511
        const int kvh = colv >> 7, d = colv & 127;
        bf16x4 t = {(bf16)acc[mt][nt][0], (bf16)acc[mt][nt][1],
                    (bf16)acc[mt][nt][2], (bf16)acc[mt][nt][3]};
        *(bf16x4*)(Vt + ((size_t)(b * NH_KV + kvh) * HD_ + d) * S_LEN + s0) = t;
      }
    }
  }
}

// ---------------- flash attention, S^T formulation --------------------------
#define KS_STRIDE 136   // 64 keys x 128 d, +8 pad (2-way banks = free)
#define VT_STRIDE 72    // 128 d x 64 keys, +8 pad

__global__ __launch_bounds__(256)
void attn_kernel(const bf16* __restrict__ Qg, const bf16* __restrict__ Kg,
                 const bf16* __restrict__ Vtg, bf16* __restrict__ Og) {
  __shared__ __align__(16) bf16 Ks[64 * KS_STRIDE];   // K tile [key][d]
  __shared__ __align__(16) bf16 Vt[128 * VT_STRIDE];  // V^T tile [d][key]
#if !HAVE_MFMA16
  __shared__ __align__(16) bf16 Pb[4][16 * 72];
#endif
  const int tid  = threadIdx.x;
  const int wave = tid >> 6, lane = tid & 63;
  const int quad = lane >> 4, l16 = lane & 15;
  const int qt = blockIdx.x, h = blockIdx.y, b = blockIdx.z;
  const int kv = h >> 2;
  const int q0 = qt * 64;
  const int tok0 = b * S_LEN;
  const float scale = 0.08838834764831845f;  // 1/sqrt(128)
  const int q = q0 + wave * 16 + l16;

  bf16x8 qf[4];
  {
    const bf16* qp = Qg + (size_t)(tok0 + q) * (NH_Q * HD_) + h * HD_ + quad * 8;
#pragma unroll
    for (int kb = 0; kb < 4; ++kb) qf[kb] = *(const bf16x8*)(qp + kb * 32);
  }

  f32x4 o[8];
#pragma unroll
  for (int dt = 0; dt < 8; ++dt) o[dt] = (f32x4){0.f, 0.f, 0.f, 0.f};
  float m_run = -__builtin_inff(), l_run = 0.f;

  int kt_begin = q0 - WIN;
  if (kt_begin < 0) kt_begin = 0;
  const int kt_end = q0 + 64;
  const bf16* vt_base = Vtg + (size_t)(b * NH_KV + kv) * HD_ * S_LEN;

  for (int kt = kt_begin; kt < kt_end; kt += 64) {
    __syncthreads();
#pragma unroll
    for (int it = 0; it < 4; ++it) {
      int vid = tid + it * 256;
      int key = vid >> 4, dblk = vid & 15;
      bf16x8 v = *(const bf16x8*)(Kg + (size_t)(tok0 + kt + key) * (NH_KV * HD_)
                                  + kv * HD_ + dblk * 8);
      *(bf16x8*)&Ks[key * KS_STRIDE + dblk * 8] = v;
    }
#pragma unroll
    for (int it = 0; it < 4; ++it) {
      int vid = tid + it * 256;
      int d = vid >> 3, kblk = vid & 7;
      bf16x8 v = *(const bf16x8*)(vt_base + (size_t)d * S_LEN + kt + kblk * 8);
      *(bf16x8*)&Vt[d * VT_STRIDE + kblk * 8] = v;
    }
    __syncthreads();

    f32x4 st[4];
#pragma unroll
    for (int nt = 0; nt < 4; ++nt) {
      f32x4 acc = (f32x4){0.f, 0.f, 0.f, 0.f};
#pragma unroll
      for (int kb = 0; kb < 4; ++kb) {
        bf16x8 kf = *(const bf16x8*)&Ks[(nt * 16 + l16) * KS_STRIDE + kb * 32 + quad * 8];
        acc = __builtin_amdgcn_mfma_f32_16x16x32_bf16(kf, qf[kb], acc, 0, 0, 0);
      }
      st[nt] = acc;
    }
#pragma unroll
    for (int nt = 0; nt < 4; ++nt)
#pragma unroll
      for (int r = 0; r < 4; ++r) {
        int key = kt + nt * 16 + quad * 4 + r;
        bool ok = (key <= q) && (key > q - WIN);
        st[nt][r] = ok ? st[nt][r] * scale : -__builtin_inff();
      }
    float mx = -__builtin_inff();
#pragma unroll
    for (int nt = 0; nt < 4; ++nt)
#pragma unroll
      for (int r = 0; r < 4; ++r) mx = fmaxf(mx, st[nt][r]);
    mx = fmaxf(mx, __shfl_xor(mx, 16, 64));
    mx = fmaxf(mx, __shfl_xor(mx, 32, 64));
    float mnew = fmaxf(m_run, mx);
    float msub = (mnew == -__builtin_inff()) ? 0.f : mnew;
    float alpha = __expf(m_run - msub);
    m_run = mnew;
    float p[4][4], psum = 0.f;
#pragma unroll
    for (int nt = 0; nt < 4; ++nt)
#pragma unroll
      for (int r = 0; r < 4; ++r) {
        p[nt][r] = __expf(st[nt][r] - msub);
        psum += p[nt][r];
      }
    psum += __shfl_xor(psum, 16, 64);
    psum += __shfl_xor(psum, 32, 64);
    l_run = l_run * alpha + psum;
#pragma unroll
    for (int dt = 0; dt < 8; ++dt) o[dt] *= alpha;

#if HAVE_MFMA16
    s16x4 pb[4];
#pragma unroll
    for (int nt = 0; nt < 4; ++nt)
#pragma unroll
      for (int r = 0; r < 4; ++r) {
        union { __bf16 h; short s; } u;
        u.h = (bf16)p[nt][r];
        pb[nt][r] = u.s;
      }
#pragma unroll
    for (int dt = 0; dt < 8; ++dt)
#pragma unroll
      for (int nt = 0; nt < 4; ++nt) {
        s16x4 vf = *(const s16x4*)&Vt[(dt * 16 + l16) * VT_STRIDE + nt * 16 + quad * 4];
        o[dt] = __builtin_amdgcn_mfma_f32_16x16x16bf16_1k(vf, pb[nt], o[dt], 0, 0, 0);
      }
#else
#pragma unroll
    for (int nt = 0; nt < 4; ++nt) {
      bf16x4 t;
#pragma unroll
      for (int r = 0; r < 4; ++r) t[r] = (bf16)p[nt][r];
      *(bf16x4*)&Pb[wave][l16 * 72 + nt * 16 + quad * 4] = t;
    }
    __syncthreads();
    bf16x8 pf[2];
    pf[0] = *(const bf16x8*)&Pb[wave][l16 * 72 + quad * 8];
    pf[1] = *(const bf16x8*)&Pb[wave][l16 * 72 + 32 + quad * 8];
#pragma unroll
    for (int dt = 0; dt < 8; ++dt)
#pragma unroll
      for (int kb = 0; kb < 2; ++kb) {
        bf16x8 vf = *(const bf16x8*)&Vt[(dt * 16 + l16) * VT_STRIDE + kb * 32 + quad * 8];
        o[dt] = __builtin_amdgcn_mfma_f32_16x16x32_bf16(vf, pf[kb], o[dt], 0, 0, 0);
      }
#endif
  }

  float inv = 1.f / l_run;
  __syncthreads();
#pragma unroll
  for (int dt = 0; dt < 8; ++dt) {
    bf16x4 t;
#pragma unroll
    for (int r = 0; r < 4; ++r) t[r] = (bf16)(o[dt][r] * inv);
    *(bf16x4*)&Ks[(wave * 16 + l16) * KS_STRIDE + dt * 16 + quad * 4] = t;
  }
  __syncthreads();
#pragma unroll
  for (int it = 0; it < 4; ++it) {
    int idx = tid + it * 256;
    int row = idx >> 4, chunk = idx & 15;
    bf16x8 v = *(const bf16x8*)&Ks[row * KS_STRIDE + chunk * 8];
    *(bf16x8*)(Og + (size_t)(tok0 + q0 + row) * (NH_Q * HD_) + h * HD_ + chunk * 8) = v;
  }
}

// ---------------- launcher ----------------
extern "C" void kernel_launch(void* const* d_in, const int* in_sizes, int n_in,
                              void* d_out, int out_size, void* d_ws, size_t ws_size,
                              hipStream_t stream) {
  const float* hs = (const float*)d_in[0];
  const float* Wq = (const float*)d_in[1];
  const float* Wk = (const float*)d_in[2];
  const float* Wv = (const float*)d_in[3];
  const float* Wo = (const float*)d_in[4];
  float* out = (float*)d_out;

  char* w = (char*)d_ws;
  bf16* hsb = (bf16*)w; w += (size_t)NTOK * 2048 * 2;   // 16.8 MB
  bf16* wqb = (bf16*)w; w += (size_t)2048 * 2048 * 2;   //  8.4 MB
  bf16* wkb = (bf16*)w; w += (size_t)512 * 2048 * 2;    //  2.1 MB
  bf16* wvb = (bf16*)w; w += (size_t)512 * 2048 * 2;    //  2.1 MB
  bf16* wob = (bf16*)w; w += (size_t)2048 * 2048 * 2;   //  8.4 MB
  bf16* qb  = (bf16*)w; w += (size_t)NTOK * 2048 * 2;   // 16.8 MB
  bf16* kb  = (bf16*)w; w += (size_t)NTOK * 512 * 2;    //  4.2 MB
  bf16* vtb = (bf16*)w; w += (size_t)NTOK * 512 * 2;    //  4.2 MB
  bf16* ab  = hsb;  // alias: hs_bf16 dead after QKV GEMM

  cvt_all<<<18874368 / 1024, 256, 0, stream>>>(hs, Wq, Wk, Wv, Wo,
                                               hsb, wqb, wkb, wvb, wob);

  gemm_qkv<<<dim3(24, NTOK / 128), 256, 0, stream>>>(hsb, wqb, wkb, wvb,
                                                     qb, kb, vtb);

  attn_kernel<<<dim3(S_LEN / 64, NH_Q, 2), 256, 0, stream>>>(qb, kb, vtb, ab);

  gemm_bt<float><<<dim3(2048 / 128, NTOK / 128), 256, 0, stream>>>(
      ab, wob, out, NTOK, 2048, 2048);
}

// Round 7
// 277.345 us; speedup vs baseline: 1.0899x; 1.0899x over previous
//
#include <hip/hip_runtime.h>
#include <cstdint>
#include <cstddef>

typedef __bf16 bf16;
typedef __attribute__((ext_vector_type(8))) __bf16 bf16x8;
typedef __attribute__((ext_vector_type(4))) __bf16 bf16x4;
typedef __attribute__((ext_vector_type(4))) float f32x4;
typedef __attribute__((ext_vector_type(4))) short s16x4;

#define S_LEN   2048
#define WIN     512
#define NH_Q    16
#define NH_KV   4
#define HD_     128
#define NTOK    4096   // B * S

#if defined(__has_builtin)
#if __has_builtin(__builtin_amdgcn_mfma_f32_16x16x16bf16_1k)
#define HAVE_MFMA16 1
#endif
#endif
#ifndef HAVE_MFMA16
#define HAVE_MFMA16 0
#endif

// s_waitcnt immediates (gfx9 encoding: vm[3:0]=s[3:0], exp=s[6:4],
// lgkm=s[11:8], vm[5:4]=s[15:14]); non-waited fields all-ones.
#define WAIT_VM40  0x8F78  // vmcnt<=40, exp/lgkm no-wait
#define WAIT_VM20  0x4F74  // vmcnt<=20
#define WAIT_VM0   0x0F70  // vmcnt<=0
#define WAIT_LGKM0 0xC07F  // lgkmcnt<=0
#define CFENCE() __asm__ __volatile__("" ::: "memory")

// async global->LDS, 16B per lane; LDS dest = wave-uniform base + lane*16
__device__ __forceinline__ void async_copy16(const void* g, void* l) {
  __builtin_amdgcn_global_load_lds(
      (const __attribute__((address_space(1))) void*)g,
      (__attribute__((address_space(3))) void*)l, 16, 0, 0);
}

// ---------------- fp32 -> bf16 convert, all 5 arrays in one launch ----------
__global__ __launch_bounds__(256)
void cvt_all(const float* __restrict__ hs, const float* __restrict__ wq,
             const float* __restrict__ wk, const float* __restrict__ wv,
             const float* __restrict__ wo, bf16* __restrict__ hsb,
             bf16* __restrict__ wqb, bf16* __restrict__ wkb,
             bf16* __restrict__ wvb, bf16* __restrict__ wob) {
  long i = ((long)blockIdx.x * 256 + threadIdx.x) * 4;  // < 18874368
  const float* in;
  bf16* out;
  if (i < 8388608)       { in = hs + i;            out = hsb + i; }
  else if (i < 12582912) { in = wq + (i - 8388608); out = wqb + (i - 8388608); }
  else if (i < 13631488) { in = wk + (i - 12582912); out = wkb + (i - 12582912); }
  else if (i < 14680064) { in = wv + (i - 13631488); out = wvb + (i - 13631488); }
  else                   { in = wo + (i - 14680064); out = wob + (i - 14680064); }
  float4 v = *(const float4*)in;
  bf16x4 t = {(bf16)v.x, (bf16)v.y, (bf16)v.z, (bf16)v.w};
  *(bf16x4*)out = t;
}

// ---------------- GEMM (barrier-style, R6): in-run CONTROL ------------------
// 128x128 tile, BK=32, dbuf, swizzled LDS (0 conflicts, R6-verified).
template <typename OutT>
__global__ __launch_bounds__(256)
void gemm_bt(const bf16* __restrict__ A, const bf16* __restrict__ W,
             OutT* __restrict__ C, int M, int N, int K) {
  __shared__ __align__(16) bf16 As[2][128 * 32];
  __shared__ __align__(16) bf16 Bs[2][128 * 32];
  const int tid  = threadIdx.x;
  const int wave = tid >> 6, lane = tid & 63;
  const int quad = lane >> 4, l16 = lane & 15;
  const int wm = wave >> 1, wn = wave & 1;
  const int m0 = blockIdx.y * 128, n0 = blockIdx.x * 128;
  const int lrow = lane >> 2;
  const int lcol = (((lane & 3) + ((lane >> 3) & 3)) & 3) * 8;  // swizzled src k
  const int gfrag = ((quad - ((l16 >> 1) & 3)) & 3) * 8;        // swizzled read k

  f32x4 acc[4][4];
#pragma unroll
  for (int i = 0; i < 4; ++i)
#pragma unroll
    for (int j = 0; j < 4; ++j) acc[i][j] = (f32x4){0.f, 0.f, 0.f, 0.f};

  auto stage = [&](int buf, int k0) {
#pragma unroll
    for (int it = 0; it < 2; ++it) {
      const int c   = it * 4 + wave;
      const int row = c * 16 + lrow;
      async_copy16(A + (size_t)(m0 + row) * K + k0 + lcol, &As[buf][c * 512]);
      async_copy16(W + (size_t)(n0 + row) * K + k0 + lcol, &Bs[buf][c * 512]);
    }
  };

  stage(0, 0);
  __syncthreads();
  for (int k0 = 0; k0 < K; k0 += 32) {
    const int cur = (k0 >> 5) & 1;
    if (k0 + 32 < K) stage(cur ^ 1, k0 + 32);
    bf16x8 af[4], bfr[4];
#pragma unroll
    for (int mt = 0; mt < 4; ++mt)
      af[mt] = *(const bf16x8*)&As[cur][(wm * 64 + mt * 16 + l16) * 32 + gfrag];
#pragma unroll
    for (int nt = 0; nt < 4; ++nt)
      bfr[nt] = *(const bf16x8*)&Bs[cur][(wn * 64 + nt * 16 + l16) * 32 + gfrag];
#pragma unroll
    for (int mt = 0; mt < 4; ++mt)
#pragma unroll
      for (int nt = 0; nt < 4; ++nt)
        acc[mt][nt] = __builtin_amdgcn_mfma_f32_16x16x32_bf16(
            af[mt], bfr[nt], acc[mt][nt], 0, 0, 0);
    __syncthreads();
  }
#pragma unroll
  for (int mt = 0; mt < 4; ++mt)
#pragma unroll
    for (int nt = 0; nt < 4; ++nt)
#pragma unroll
      for (int r = 0; r < 4; ++r) {
        const int row = m0 + wm * 64 + mt * 16 + quad * 4 + r;
        const int col = n0 + wn * 64 + nt * 16 + l16;
        C[(size_t)row * N + col] = (OutT)acc[mt][nt][r];
      }
}

// ---------------- fused QKV GEMM: producer/consumer wave specialization -----
// 448 threads: waves 0-5 consume (2x3 of 64x64 -> 128x192 tile), wave 6
// produces all global_load_lds into a 3-slot LDS ring. NO __syncthreads in
// the K-loop -> no all-wave vmcnt(0) drain (the m97 plateau). Producer
// publishes slot g after s_waitcnt vmcnt(40) (gens g-1,g stay in flight --
// AITER-style "never vmcnt(0)"). Flags: ready[slot] token (volatile spin,
// same-address broadcast = free), done[slot] atomic inc gates slot reuse.
// Grid 16x32 = 512 blocks = exactly 2/CU (balanced); LDS 60KB*2 <= 160KB.
__global__ __launch_bounds__(448, 4)
void gemm_qkv(const bf16* __restrict__ A, const bf16* __restrict__ Wq,
              const bf16* __restrict__ Wk, const bf16* __restrict__ Wv,
              bf16* __restrict__ Qo, bf16* __restrict__ Ko,
              bf16* __restrict__ Vt) {
  __shared__ __align__(16) bf16 As[3][128 * 32];  // 8 KB/slot
  __shared__ __align__(16) bf16 Bs[3][192 * 32];  // 12 KB/slot
  __shared__ int ready[3];
  __shared__ int done[3];
  const int tid = threadIdx.x, wave = tid >> 6, lane = tid & 63;
  const int quad = lane >> 4, l16 = lane & 15;
  const int bx = blockIdx.x;          // 16 tiles x 192 cols over N=3072
  const int m0 = blockIdx.y * 128;
  if (tid < 3) ready[tid] = 0;
  else if (tid < 6) done[tid - 3] = 0;
  __syncthreads();
  volatile int* vready = ready;
  volatile int* vdone  = done;
  const int R = 64;                   // K/32 generations

  if (wave == 6) {
    // ------------- producer -------------
    const int lrow = lane >> 2;
    const int lcol = (((lane & 3) + ((lane >> 3) & 3)) & 3) * 8;  // swizzle
    const bf16* arow = A + (size_t)(m0 + lrow) * 2048 + lcol;
    const bf16* brow[12];
#pragma unroll
    for (int c = 0; c < 12; ++c) {
      const int n = bx * 192 + c * 16 + lrow;  // region boundaries 16-aligned
      brow[c] = (n < 2048 ? Wq + (size_t)n * 2048
               : n < 2560 ? Wk + (size_t)(n - 2048) * 2048
                          : Wv + (size_t)(n - 2560) * 2048) + lcol;
    }
    int slot = 0, pslot = 0, need = 0;
    for (int g = 0; g < R; ++g) {
      if (slot == 0 && g) need += 6;  // need = 6*floor(g/3): slot reuse gate
      while (vdone[slot] < need) __builtin_amdgcn_s_sleep(1);
      const int k0 = g * 32;
#pragma unroll
      for (int c = 0; c < 8; ++c)
        async_copy16(arow + (size_t)c * 16 * 2048 + k0, &As[slot][c * 512]);
#pragma unroll
      for (int c = 0; c < 12; ++c)
        async_copy16(brow[c] + k0, &Bs[slot][c * 512]);
      __builtin_amdgcn_s_waitcnt(WAIT_VM40);   // gen g-2 retired (20/gen)
      if (g >= 2) {
        if (lane == 0) vready[pslot] = g - 1;  // token (g-2)+1
        pslot = pslot == 2 ? 0 : pslot + 1;
      }
      slot = slot == 2 ? 0 : slot + 1;
    }
    __builtin_amdgcn_s_waitcnt(WAIT_VM20);     // drain gen R-2
    if (lane == 0) vready[pslot] = R - 1;
    pslot = pslot == 2 ? 0 : pslot + 1;
    __builtin_amdgcn_s_waitcnt(WAIT_VM0);      // drain gen R-1
    if (lane == 0) vready[pslot] = R;
    return;  // producer skips epilogue
  }

  // ------------- consumers: (wm,wn) = (wave/3, wave%3), 64x64 each ----------
  const int wm = wave / 3, wn = wave % 3;
  const int gfrag = ((quad - ((l16 >> 1) & 3)) & 3) * 8;  // swizzled read k
  f32x4 acc[4][4];
#pragma unroll
  for (int i = 0; i < 4; ++i)
#pragma unroll
    for (int j = 0; j < 4; ++j) acc[i][j] = (f32x4){0.f, 0.f, 0.f, 0.f};

  int slot = 0;
  for (int g = 0; g < R; ++g) {
    while (vready[slot] < g + 1) __builtin_amdgcn_s_sleep(1);
    CFENCE();
    bf16x8 af[4], bfr[4];
#pragma unroll
    for (int mt = 0; mt < 4; ++mt)
      af[mt] = *(const bf16x8*)&As[slot][(wm * 64 + mt * 16 + l16) * 32 + gfrag];
#pragma unroll
    for (int nt = 0; nt < 4; ++nt)
      bfr[nt] = *(const bf16x8*)&Bs[slot][(wn * 64 + nt * 16 + l16) * 32 + gfrag];
#pragma unroll
    for (int mt = 0; mt < 4; ++mt)
#pragma unroll
      for (int nt = 0; nt < 4; ++nt)
        acc[mt][nt] = __builtin_amdgcn_mfma_f32_16x16x32_bf16(
            af[mt], bfr[nt], acc[mt][nt], 0, 0, 0);
    __builtin_amdgcn_s_waitcnt(WAIT_LGKM0);  // frag reads retired before signal
    CFENCE();
    if (lane == 0) atomicAdd(&done[slot], 1);
    slot = slot == 2 ? 0 : slot + 1;
  }

  // epilogue: RoPE on head-first-half chunks of Q/K, then region stores
  const int cbase = bx * 192 + wn * 64;
  if (cbase < 2560 && (cbase & 127) == 0) {  // Q/K chunk covering d=0..63
#pragma unroll
    for (int nt = 0; nt < 2; ++nt) {
      const int d = nt * 16 + l16;  // 0..31, pairs with acc[mt][nt+2]
      const float invf = exp2f(-(float)d * 0.41524101186091903f);  // 1e4^(-d/32)
#pragma unroll
      for (int mt = 0; mt < 4; ++mt)
#pragma unroll
        for (int r = 0; r < 4; ++r) {
          const int pos = (m0 + wm * 64 + mt * 16 + quad * 4 + r) & (S_LEN - 1);
          float s, c;
          __sincosf((float)pos * invf, &s, &c);
          const float x1 = acc[mt][nt][r], x2 = acc[mt][nt + 2][r];
          acc[mt][nt][r]     = x1 * c - x2 * s;
          acc[mt][nt + 2][r] = x2 * c + x1 * s;
        }
    }
  }
#pragma unroll
  for (int mt = 0; mt < 4; ++mt) {
    const int row0 = m0 + wm * 64 + mt * 16 + quad * 4;
#pragma unroll
    for (int nt = 0; nt < 4; ++nt) {
      const int col16 = cbase + nt * 16;  // 16-col chunk, region-uniform
      if (col16 < 2048) {                 // Q: [tok][2048]
#pragma unroll
        for (int r = 0; r < 4; ++r)
          Qo[(size_t)(row0 + r) * 2048 + col16 + l16] = (bf16)acc[mt][nt][r];
      } else if (col16 < 2560) {          // K: [tok][512]
#pragma unroll
        for (int r = 0; r < 4; ++r)
          Ko[(size_t)(row0 + r) * 512 + col16 - 2048 + l16] = (bf16)acc[mt][nt][r];
      } else {                            // V: transposed vt[(b*4+kv)*128+d][s]
        const int colv = col16 + l16 - 2560;
        const int b = row0 >> 11, s0 = row0 & (S_LEN - 1);
        bf16x4 t = {(bf16)acc[mt][nt][0], (bf16)acc[mt][nt][1],
                    (bf16)acc[mt][nt][2], (bf16)acc[mt][nt][3]};
        *(bf16x4*)(Vt + ((size_t)(b * NH_KV + (colv >> 7)) * HD_ + (colv & 127))
                        * S_LEN + s0) = t;
      }
    }
  }
}

// ---------------- flash attention, S^T formulation --------------------------
#define KS_STRIDE 136   // 64 keys x 128 d, +8 pad (2-way banks = free)
#define VT_STRIDE 72    // 128 d x 64 keys, +8 pad

__global__ __launch_bounds__(256)
void attn_kernel(const bf16* __restrict__ Qg, const bf16* __restrict__ Kg,
                 const bf16* __restrict__ Vtg, bf16* __restrict__ Og) {
  __shared__ __align__(16) bf16 Ks[64 * KS_STRIDE];   // K tile [key][d]
  __shared__ __align__(16) bf16 Vt[128 * VT_STRIDE];  // V^T tile [d][key]
#if !HAVE_MFMA16
  __shared__ __align__(16) bf16 Pb[4][16 * 72];
#endif
  const int tid  = threadIdx.x;
  const int wave = tid >> 6, lane = tid & 63;
  const int quad = lane >> 4, l16 = lane & 15;
  const int qt = blockIdx.x, h = blockIdx.y, b = blockIdx.z;
  const int kv = h >> 2;
  const int q0 = qt * 64;
  const int tok0 = b * S_LEN;
  const float scale = 0.08838834764831845f;  // 1/sqrt(128)
  const int q = q0 + wave * 16 + l16;

  bf16x8 qf[4];
  {
    const bf16* qp = Qg + (size_t)(tok0 + q) * (NH_Q * HD_) + h * HD_ + quad * 8;
#pragma unroll
    for (int kb = 0; kb < 4; ++kb) qf[kb] = *(const bf16x8*)(qp + kb * 32);
  }

  f32x4 o[8];
#pragma unroll
  for (int dt = 0; dt < 8; ++dt) o[dt] = (f32x4){0.f, 0.f, 0.f, 0.f};
  float m_run = -__builtin_inff(), l_run = 0.f;

  int kt_begin = q0 - WIN;
  if (kt_begin < 0) kt_begin = 0;
  const int kt_end = q0 + 64;
  const bf16* vt_base = Vtg + (size_t)(b * NH_KV + kv) * HD_ * S_LEN;

  for (int kt = kt_begin; kt < kt_end; kt += 64) {
    __syncthreads();
#pragma unroll
    for (int it = 0; it < 4; ++it) {
      int vid = tid + it * 256;
      int key = vid >> 4, dblk = vid & 15;
      bf16x8 v = *(const bf16x8*)(Kg + (size_t)(tok0 + kt + key) * (NH_KV * HD_)
                                  + kv * HD_ + dblk * 8);
      *(bf16x8*)&Ks[key * KS_STRIDE + dblk * 8] = v;
    }
#pragma unroll
    for (int it = 0; it < 4; ++it) {
      int vid = tid + it * 256;
      int d = vid >> 3, kblk = vid & 7;
      bf16x8 v = *(const bf16x8*)(vt_base + (size_t)d * S_LEN + kt + kblk * 8);
      *(bf16x8*)&Vt[d * VT_STRIDE + kblk * 8] = v;
    }
    __syncthreads();

    f32x4 st[4];
#pragma unroll
    for (int nt = 0; nt < 4; ++nt) {
      f32x4 acc = (f32x4){0.f, 0.f, 0.f, 0.f};
#pragma unroll
      for (int kb = 0; kb < 4; ++kb) {
        bf16x8 kf = *(const bf16x8*)&Ks[(nt * 16 + l16) * KS_STRIDE + kb * 32 + quad * 8];
        acc = __builtin_amdgcn_mfma_f32_16x16x32_bf16(kf, qf[kb], acc, 0, 0, 0);
      }
      st[nt] = acc;
    }
#pragma unroll
    for (int nt = 0; nt < 4; ++nt)
#pragma unroll
      for (int r = 0; r < 4; ++r) {
        int key = kt + nt * 16 + quad * 4 + r;
        bool ok = (key <= q) && (key > q - WIN);
        st[nt][r] = ok ? st[nt][r] * scale : -__builtin_inff();
      }
    float mx = -__builtin_inff();
#pragma unroll
    for (int nt = 0; nt < 4; ++nt)
#pragma unroll
      for (int r = 0; r < 4; ++r) mx = fmaxf(mx, st[nt][r]);
    mx = fmaxf(mx, __shfl_xor(mx, 16, 64));
    mx = fmaxf(mx, __shfl_xor(mx, 32, 64));
    float mnew = fmaxf(m_run, mx);
    float msub = (mnew == -__builtin_inff()) ? 0.f : mnew;
    float alpha = __expf(m_run - msub);
    m_run = mnew;
    float p[4][4], psum = 0.f;
#pragma unroll
    for (int nt = 0; nt < 4; ++nt)
#pragma unroll
      for (int r = 0; r < 4; ++r) {
        p[nt][r] = __expf(st[nt][r] - msub);
        psum += p[nt][r];
      }
    psum += __shfl_xor(psum, 16, 64);
    psum += __shfl_xor(psum, 32, 64);
    l_run = l_run * alpha + psum;
#pragma unroll
    for (int dt = 0; dt < 8; ++dt) o[dt] *= alpha;

#if HAVE_MFMA16
    s16x4 pb[4];
#pragma unroll
    for (int nt = 0; nt < 4; ++nt)
#pragma unroll
      for (int r = 0; r < 4; ++r) {
        union { __bf16 h; short s; } u;
        u.h = (bf16)p[nt][r];
        pb[nt][r] = u.s;
      }
#pragma unroll
    for (int dt = 0; dt < 8; ++dt)
#pragma unroll
      for (int nt = 0; nt < 4; ++nt) {
        s16x4 vf = *(const s16x4*)&Vt[(dt * 16 + l16) * VT_STRIDE + nt * 16 + quad * 4];
        o[dt] = __builtin_amdgcn_mfma_f32_16x16x16bf16_1k(vf, pb[nt], o[dt], 0, 0, 0);
      }
#else
#pragma unroll
    for (int nt = 0; nt < 4; ++nt) {
      bf16x4 t;
#pragma unroll
      for (int r = 0; r < 4; ++r) t[r] = (bf16)p[nt][r];
      *(bf16x4*)&Pb[wave][l16 * 72 + nt * 16 + quad * 4] = t;
    }
    __syncthreads();
    bf16x8 pf[2];
    pf[0] = *(const bf16x8*)&Pb[wave][l16 * 72 + quad * 8];
    pf[1] = *(const bf16x8*)&Pb[wave][l16 * 72 + 32 + quad * 8];
#pragma unroll
    for (int dt = 0; dt < 8; ++dt)
#pragma unroll
      for (int kb = 0; kb < 2; ++kb) {
        bf16x8 vf = *(const bf16x8*)&Vt[(dt * 16 + l16) * VT_STRIDE + kb * 32 + quad * 8];
        o[dt] = __builtin_amdgcn_mfma_f32_16x16x32_bf16(vf, pf[kb], o[dt], 0, 0, 0);
      }
#endif
  }

  float inv = 1.f / l_run;
  __syncthreads();
#pragma unroll
  for (int dt = 0; dt < 8; ++dt) {
    bf16x4 t;
#pragma unroll
    for (int r = 0; r < 4; ++r) t[r] = (bf16)(o[dt][r] * inv);
    *(bf16x4*)&Ks[(wave * 16 + l16) * KS_STRIDE + dt * 16 + quad * 4] = t;
  }
  __syncthreads();
#pragma unroll
  for (int it = 0; it < 4; ++it) {
    int idx = tid + it * 256;
    int row = idx >> 4, chunk = idx & 15;
    bf16x8 v = *(const bf16x8*)&Ks[row * KS_STRIDE + chunk * 8];
    *(bf16x8*)(Og + (size_t)(tok0 + q0 + row) * (NH_Q * HD_) + h * HD_ + chunk * 8) = v;
  }
}

// ---------------- launcher ----------------
extern "C" void kernel_launch(void* const* d_in, const int* in_sizes, int n_in,
                              void* d_out, int out_size, void* d_ws, size_t ws_size,
                              hipStream_t stream) {
  const float* hs = (const float*)d_in[0];
  const float* Wq = (const float*)d_in[1];
  const float* Wk = (const float*)d_in[2];
  const float* Wv = (const float*)d_in[3];
  const float* Wo = (const float*)d_in[4];
  float* out = (float*)d_out;

  char* w = (char*)d_ws;
  bf16* hsb = (bf16*)w; w += (size_t)NTOK * 2048 * 2;   // 16.8 MB
  bf16* wqb = (bf16*)w; w += (size_t)2048 * 2048 * 2;   //  8.4 MB
  bf16* wkb = (bf16*)w; w += (size_t)512 * 2048 * 2;    //  2.1 MB
  bf16* wvb = (bf16*)w; w += (size_t)512 * 2048 * 2;    //  2.1 MB
  bf16* wob = (bf16*)w; w += (size_t)2048 * 2048 * 2;   //  8.4 MB
  bf16* qb  = (bf16*)w; w += (size_t)NTOK * 2048 * 2;   // 16.8 MB
  bf16* kb  = (bf16*)w; w += (size_t)NTOK * 512 * 2;    //  4.2 MB
  bf16* vtb = (bf16*)w; w += (size_t)NTOK * 512 * 2;    //  4.2 MB
  bf16* ab  = hsb;  // alias: hs_bf16 dead after QKV GEMM

  cvt_all<<<18874368 / 1024, 256, 0, stream>>>(hs, Wq, Wk, Wv, Wo,
                                               hsb, wqb, wkb, wvb, wob);

  gemm_qkv<<<dim3(16, NTOK / 128), 448, 0, stream>>>(hsb, wqb, wkb, wvb,
                                                     qb, kb, vtb);

  attn_kernel<<<dim3(S_LEN / 64, NH_Q, 2), 256, 0, stream>>>(qb, kb, vtb, ab);

  gemm_bt<float><<<dim3(2048 / 128, NTOK / 128), 256, 0, stream>>>(
      ab, wob, out, NTOK, 2048, 2048);
}